// Round 2
// baseline (427.521 us; speedup 1.0000x reference)
//
#include <hip/hip_runtime.h>

typedef __attribute__((ext_vector_type(4))) unsigned int u32x4;
typedef __attribute__((ext_vector_type(8))) short s16x8;
typedef __attribute__((ext_vector_type(4))) float f32x4;

union V16 { u32x4 u; s16x8 s; };

#define CAND_W 1.2e-4f

__device__ __forceinline__ unsigned short f2bf(float x) {
    unsigned int u = __float_as_uint(x);
    u += 0x7fffu + ((u >> 16) & 1u);          // round-to-nearest-even bf16
    return (unsigned short)(u >> 16);
}
__device__ __forceinline__ float bf2f(unsigned short h) {
    return __uint_as_float(((unsigned int)h) << 16);
}

// ---------------------------------------------------------------------------
// prep_a: z_e [16,256,32,32] fp32 NCHW -> A fragments, scaled by -2, split
// into bf16 hi/lo, MFMA A-layout: lane l of row-tile rt, k-step j holds
// A[rt*16+(l&15)][k = j*32 + (l>>4)*8 .. +8]
// ---------------------------------------------------------------------------
__global__ void prep_a(const float* __restrict__ z,
                       u32x4* __restrict__ ahi, u32x4* __restrict__ alo) {
    int o = blockIdx.x * 256 + threadIdx.x;       // 524288 total
    int l = o & 63, j = (o >> 6) & 7, rt = o >> 9;
    int n = rt * 16 + (l & 15);                   // row = b*1024 + h*32 + w
    int d0 = j * 32 + ((l >> 4) << 3);
    const float* src = z + ((size_t)(n >> 10) * 256 + d0) * 1024 + (n & 1023);
    V16 vh, vl;
#pragma unroll
    for (int i = 0; i < 8; ++i) {
        float x = -2.0f * src[(size_t)i * 1024];
        unsigned short h = f2bf(x);
        vh.s[i] = (short)h;
        vl.s[i] = (short)f2bf(x - bf2f(h));
    }
    ahi[o] = vh.u;
    alo[o] = vl.u;
}

// ---------------------------------------------------------------------------
// prep_b: codebook [8192,256] fp32 -> bf16 hi/lo B fragments, stream layout:
// uint4 index ((t*8 + j)*2 + s)*64 + l  (s=0 hi, s=1 lo)
// ---------------------------------------------------------------------------
__global__ void prep_b(const float* __restrict__ cb, u32x4* __restrict__ bstr) {
    int o = blockIdx.x * 256 + threadIdx.x;       // 262144 total
    int l = o & 63, j = (o >> 6) & 7, t = o >> 9;
    int code = t * 16 + (l & 15);
    int d0 = j * 32 + ((l >> 4) << 3);
    const float* src = cb + (size_t)code * 256 + d0;
    V16 vh, vl;
#pragma unroll
    for (int i = 0; i < 8; ++i) {
        float x = src[i];
        unsigned short h = f2bf(x);
        vh.s[i] = (short)h;
        vl.s[i] = (short)f2bf(x - bf2f(h));
    }
    size_t base = (size_t)(t * 8 + j) * 128 + l;
    bstr[base] = vh.u;
    bstr[base + 64] = vl.u;
}

// ---------------------------------------------------------------------------
// c2[k] = sum_d cb[k][d]^2 (f32), one wave per code
// ---------------------------------------------------------------------------
__global__ void calc_c2(const float* __restrict__ cb, float* __restrict__ c2) {
    int wid = threadIdx.x >> 6, lane = threadIdx.x & 63;
    int code = blockIdx.x * 4 + wid;
    const float* row = cb + (size_t)code * 256;
    float s = 0.f;
#pragma unroll
    for (int q = 0; q < 4; ++q) { float v = row[q * 64 + lane]; s += v * v; }
#pragma unroll
    for (int m = 32; m >= 1; m >>= 1) s += __shfl_xor(s, m, 64);
    if (lane == 0) c2[code] = s;
}

// ---------------------------------------------------------------------------
// vq_main (stage 1): wave handles 16 rows (A frags in VGPRs), scans all 8192
// codes in chunks of 64, double-buffered LDS. Tracks TOP-2 (dist,idx) per
// lane per row; 16 lanes x 2 = 32 candidates/row written to ws.
// ---------------------------------------------------------------------------
typedef __attribute__((address_space(1))) unsigned int gu32;
typedef __attribute__((address_space(3))) unsigned int lu32;

__global__ __launch_bounds__(256)
void vq_main(const u32x4* __restrict__ ahi4, const u32x4* __restrict__ alo4,
             const u32x4* __restrict__ bstr, const float* __restrict__ c2,
             float* __restrict__ cd, int* __restrict__ ci) {
    __shared__ u32x4 lds[2][4096];                // 2 x 64 KB
    int wid = threadIdx.x >> 6, lane = threadIdx.x & 63;
    int rt = blockIdx.x * 4 + wid;                // global 16-row tile
    int colc = lane & 15;

    V16 ah[8], al[8];
#pragma unroll
    for (int j = 0; j < 8; ++j) {
        ah[j].u = ahi4[(size_t)(rt * 8 + j) * 64 + lane];
        al[j].u = alo4[(size_t)(rt * 8 + j) * 64 + lane];
    }

    float m1[4] = {3.4e38f, 3.4e38f, 3.4e38f, 3.4e38f};
    float m2[4] = {3.4e38f, 3.4e38f, 3.4e38f, 3.4e38f};
    int   i1[4] = {0, 0, 0, 0};
    int   i2[4] = {0, 0, 0, 0};

    auto stage = [&](int ch, int buf) {
        const u32x4* g = bstr + (size_t)ch * 4096 + wid * 1024 + lane;
        u32x4* d = &lds[buf][wid * 1024];
#pragma unroll
        for (int it = 0; it < 16; ++it) {
            __builtin_amdgcn_global_load_lds((const gu32*)(g + it * 64),
                                             (lu32*)(d + it * 64), 16, 0, 0);
        }
    };

    stage(0, 0);
    __syncthreads();

    for (int ch = 0; ch < 128; ++ch) {
        int cur = ch & 1;
        if (ch + 1 < 128) stage(ch + 1, cur ^ 1);

        f32x4 acc[4];
        float c2v[4];
#pragma unroll
        for (int t = 0; t < 4; ++t) {
            acc[t] = (f32x4){0.f, 0.f, 0.f, 0.f};
            c2v[t] = c2[(ch * 4 + t) * 16 + colc];
        }
#pragma unroll
        for (int j = 0; j < 8; ++j) {
#pragma unroll
            for (int t = 0; t < 4; ++t) {         // 4 independent acc chains
                V16 bh, bl;
                bh.u = lds[cur][((t * 8 + j) * 2 + 0) * 64 + lane];
                bl.u = lds[cur][((t * 8 + j) * 2 + 1) * 64 + lane];
                acc[t] = __builtin_amdgcn_mfma_f32_16x16x32_bf16(ah[j].s, bh.s, acc[t], 0, 0, 0);
                acc[t] = __builtin_amdgcn_mfma_f32_16x16x32_bf16(al[j].s, bh.s, acc[t], 0, 0, 0);
                acc[t] = __builtin_amdgcn_mfma_f32_16x16x32_bf16(ah[j].s, bl.s, acc[t], 0, 0, 0);
            }
        }
#pragma unroll
        for (int t = 0; t < 4; ++t) {
            int code = (ch * 4 + t) * 16 + colc;
#pragma unroll
            for (int r = 0; r < 4; ++r) {
                float d = acc[t][r] + c2v[t];
                bool lt1 = d < m1[r];
                bool lt2 = d < m2[r];
                m2[r] = lt1 ? m1[r] : (lt2 ? d : m2[r]);
                i2[r] = lt1 ? i1[r] : (lt2 ? code : i2[r]);
                m1[r] = lt1 ? d : m1[r];
                i1[r] = lt1 ? code : i1[r];
            }
        }
        __syncthreads();                          // joins waves + drains lds loads
    }

#pragma unroll
    for (int r = 0; r < 4; ++r) {
        int row = rt * 16 + (lane >> 4) * 4 + r;
        int base = row * 32 + colc * 2;
        cd[base]     = m1[r];  ci[base]     = i1[r];
        cd[base + 1] = m2[r];  ci[base + 1] = i2[r];
    }
}

// ---------------------------------------------------------------------------
// prep_zt: exact z transposed to row-major [16384][256] + z2f = (f32)sum z^2
// (f64 accumulate). Runs AFTER vq_main; overwrites the (dead) ahi/alo region.
// ---------------------------------------------------------------------------
__global__ void prep_zt(const float* __restrict__ z, float* __restrict__ zt,
                        float* __restrict__ z2f) {
    __shared__ float tile[32][257];
    int b = blockIdx.x >> 5, h = blockIdx.x & 31;
    int tid = threadIdx.x;
    for (int e = tid; e < 8192; e += 256) {
        int d = e >> 5, w = e & 31;
        tile[w][d] = z[((size_t)(b * 256 + d) * 32 + h) * 32 + w];
    }
    __syncthreads();
    for (int e = tid; e < 8192; e += 256) {
        int w = e >> 8, d = e & 255;
        zt[((size_t)(b * 1024 + h * 32 + w)) * 256 + d] = tile[w][d];
    }
    if (tid < 32) {
        double s = 0.0;
        for (int d = 0; d < 256; ++d) { double v = (double)tile[tid][d]; s += v * v; }
        z2f[b * 1024 + h * 32 + tid] = (float)s;
    }
}

// ---------------------------------------------------------------------------
// refine (stage 2): one wave per row. Emulate np float32 semantics exactly:
// dot in f64 (exact), then d1 = fl32(z2 - 2*Mf); d2 = fl32(d1 + c2).
// Argmin over window candidates with first-index tie-break.
// ---------------------------------------------------------------------------
__global__ __launch_bounds__(256)
void refine(const float* __restrict__ zt, const float* __restrict__ z2f,
            const float* __restrict__ cb, const float* __restrict__ c2,
            const float* __restrict__ cd, const int* __restrict__ ci,
            float* __restrict__ out, int* __restrict__ idxi) {
    int wid = threadIdx.x >> 6, lane = threadIdx.x & 63;
    int n = blockIdx.x * 4 + wid;
    float zq[4];
#pragma unroll
    for (int q = 0; q < 4; ++q) zq[q] = zt[(size_t)n * 256 + q * 64 + lane];
    float z2v = z2f[n];
    float cdv = 3.4e38f; int civ = 0;
    if (lane < 32) { cdv = cd[n * 32 + lane]; civ = ci[n * 32 + lane]; }
    float rowmin = cdv;
#pragma unroll
    for (int m = 32; m >= 1; m >>= 1) rowmin = fminf(rowmin, __shfl_xor(rowmin, m, 64));
    bool active = (lane < 32) && (cdv <= rowmin + CAND_W);
    unsigned long long mask = __ballot(active);
    float bestd = 3.4e38f; int besti = 0x7fffffff;
    while (mask) {
        int k = __ffsll(mask) - 1;
        mask &= mask - 1;
        int cidx = __shfl(civ, k, 64);
        const float* crow = cb + (size_t)cidx * 256;
        double dot = 0.0;
#pragma unroll
        for (int q = 0; q < 4; ++q)
            dot += (double)zq[q] * (double)crow[q * 64 + lane];
#pragma unroll
        for (int m = 32; m >= 1; m >>= 1) dot += __shfl_xor(dot, m, 64);
        float Mf = (float)dot;                    // exact dot rounded once to f32
        float d1 = z2v - 2.0f * Mf;               // np: z2 - 2.0*M  (f32 op)
        float d2 = d1 + c2[cidx];                 // np: ... + c2    (f32 op)
        if (d2 < bestd || (d2 == bestd && cidx < besti)) { bestd = d2; besti = cidx; }
    }
    if (lane == 0) {
        idxi[n] = besti;
        out[4194304 + n] = (float)besti;
    }
}

// ---------------------------------------------------------------------------
// gather: z_q[b,d,h,w] = codebook[idx[b,h,w]][d], LDS transpose per (b,h)
// ---------------------------------------------------------------------------
__global__ void gather_out(const float* __restrict__ cb,
                           const int* __restrict__ idxi,
                           float* __restrict__ out) {
    __shared__ float tile[32][257];
    __shared__ int sidx[32];
    int b = blockIdx.x >> 5, h = blockIdx.x & 31;
    int tid = threadIdx.x;
    if (tid < 32) sidx[tid] = idxi[(b * 32 + h) * 32 + tid];
    __syncthreads();
    for (int e = tid; e < 8192; e += 256) {
        int w = e >> 8, d = e & 255;
        tile[w][d] = cb[(size_t)sidx[w] * 256 + d];
    }
    __syncthreads();
    for (int e = tid; e < 8192; e += 256) {
        int d = e >> 5, w = e & 31;
        out[(((size_t)b * 256 + d) * 32 + h) * 32 + w] = tile[w][d];
    }
}

// ---------------------------------------------------------------------------
extern "C" void kernel_launch(void* const* d_in, const int* in_sizes, int n_in,
                              void* d_out, int out_size, void* d_ws, size_t ws_size,
                              hipStream_t stream) {
    const float* z  = (const float*)d_in[0];      // [16,256,32,32]
    const float* cb = (const float*)d_in[1];      // [8192,256]
    float* out = (float*)d_out;                   // z_q (4194304) + idx (16384)
    char* w = (char*)d_ws;
    // ws layout:
    //   [0,16M)      ahi(8M)+alo(8M)  -- later reused as zt (16M)
    //   [16M,24M)    bstr 8M
    //   [24M+..]     c2 32K | cd 2M | ci 2M | z2f 64K | idxi 64K
    u32x4* ahi  = (u32x4*)(w);
    u32x4* alo  = (u32x4*)(w + 8388608);
    float* zt   = (float*)(w);                    // aliases ahi/alo (dead then)
    u32x4* bstr = (u32x4*)(w + 16777216);
    float* c2   = (float*)(w + 25165824);
    float* cd   = (float*)(w + 25198592);
    int*   ci   = (int*)  (w + 27295744);
    float* z2f  = (float*)(w + 29392896);
    int*   idxi = (int*)  (w + 29458432);

    prep_a<<<2048, 256, 0, stream>>>(z, ahi, alo);
    prep_b<<<1024, 256, 0, stream>>>(cb, bstr);
    calc_c2<<<2048, 256, 0, stream>>>(cb, c2);
    vq_main<<<256, 256, 0, stream>>>(ahi, alo, bstr, c2, cd, ci);
    prep_zt<<<512, 256, 0, stream>>>(z, zt, z2f);   // after vq_main: reuses ws
    refine<<<4096, 256, 0, stream>>>(zt, z2f, cb, c2, cd, ci, out, idxi);
    gather_out<<<512, 256, 0, stream>>>(cb, idxi, out);
}

// Round 3
// 230.641 us; speedup vs baseline: 1.8536x; 1.8536x over previous
//
#include <hip/hip_runtime.h>

typedef __attribute__((ext_vector_type(4))) unsigned int u32x4;
typedef __attribute__((ext_vector_type(8))) short s16x8;
typedef __attribute__((ext_vector_type(4))) float f32x4;

union V16 { u32x4 u; s16x8 s; };

#define CAND_W 2.5e-4f
#define FINF 3.4e38f

__device__ __forceinline__ unsigned short f2bf(float x) {
    unsigned int u = __float_as_uint(x);
    u += 0x7fffu + ((u >> 16) & 1u);          // round-to-nearest-even bf16
    return (unsigned short)(u >> 16);
}

// ---------------------------------------------------------------------------
// prep_a: z_e [16,256,32,32] fp32 NCHW -> bf16 A fragments scaled by -2.
// MFMA A-layout: lane l of row-tile rt, k-step j holds
// A[rt*16+(l&15)][k = j*32 + (l>>4)*8 .. +8]   (verified by R2 pass)
// ---------------------------------------------------------------------------
__global__ void prep_a(const float* __restrict__ z, u32x4* __restrict__ ahi) {
    int o = blockIdx.x * 256 + threadIdx.x;       // 524288 total
    int l = o & 63, j = (o >> 6) & 7, rt = o >> 9;
    int n = rt * 16 + (l & 15);                   // row = b*1024 + h*32 + w
    int d0 = j * 32 + ((l >> 4) << 3);
    const float* src = z + ((size_t)(n >> 10) * 256 + d0) * 1024 + (n & 1023);
    V16 vh;
#pragma unroll
    for (int i = 0; i < 8; ++i)
        vh.s[i] = (short)f2bf(-2.0f * src[(size_t)i * 1024]);
    ahi[o] = vh.u;
}

// ---------------------------------------------------------------------------
// prep_b: codebook [8192,256] fp32 -> bf16 B fragments, stream layout:
// uint4 index (t*8 + j)*64 + l ; lane l holds cb[t*16+(l&15)][j*32+(l>>4)*8..+8]
// ---------------------------------------------------------------------------
__global__ void prep_b(const float* __restrict__ cb, u32x4* __restrict__ bstr) {
    int o = blockIdx.x * 256 + threadIdx.x;       // 262144 total
    int l = o & 63, j = (o >> 6) & 7, t = o >> 9;
    int code = t * 16 + (l & 15);
    int d0 = j * 32 + ((l >> 4) << 3);
    const float* src = cb + (size_t)code * 256 + d0;
    V16 vh;
#pragma unroll
    for (int i = 0; i < 8; ++i) vh.s[i] = (short)f2bf(src[i]);
    bstr[(size_t)(t * 8 + j) * 64 + l] = vh.u;
}

// ---------------------------------------------------------------------------
// c2[k] = sum_d cb[k][d]^2 (f32), one wave per code
// ---------------------------------------------------------------------------
__global__ void calc_c2(const float* __restrict__ cb, float* __restrict__ c2) {
    int wid = threadIdx.x >> 6, lane = threadIdx.x & 63;
    int code = blockIdx.x * 4 + wid;
    const float* row = cb + (size_t)code * 256;
    float s = 0.f;
#pragma unroll
    for (int q = 0; q < 4; ++q) { float v = row[q * 64 + lane]; s += v * v; }
#pragma unroll
    for (int m = 32; m >= 1; m >>= 1) s += __shfl_xor(s, m, 64);
    if (lane == 0) c2[code] = s;
}

// ---------------------------------------------------------------------------
// vq_main (stage 1): 512 wgs = 64 rowgroups x 8 code-stripes (stripe=bid&7
// -> per-XCD L2 locality). Wave holds 4 row-tiles (64 rows) of A in VGPRs,
// scans its 1024-code stripe in 32 chunks of 32 codes, double-buffered LDS
// (2x16KB). c2 folded into MFMA C-init. Top-2 per lane per row-slot, then
// cross-lane extraction of top-4 per row per stripe -> 32 cand/row total.
// ---------------------------------------------------------------------------
typedef __attribute__((address_space(1))) unsigned int gu32;
typedef __attribute__((address_space(3))) unsigned int lu32;

__global__ __launch_bounds__(256, 2)
void vq_main(const u32x4* __restrict__ ahi4, const u32x4* __restrict__ bstr,
             const float* __restrict__ c2,
             float* __restrict__ cd, int* __restrict__ ci) {
    __shared__ u32x4 lds[2][1024];                // 2 x 16 KB
    int tid = threadIdx.x;
    int wid = tid >> 6, lane = tid & 63;
    int stripe = blockIdx.x & 7;
    int rg = blockIdx.x >> 3;                     // 0..63
    int colc = lane & 15;
    int rt0 = rg * 16 + wid * 4;                  // first of this wave's 4 row-tiles

    V16 ah[4][8];
#pragma unroll
    for (int rt = 0; rt < 4; ++rt)
#pragma unroll
        for (int j = 0; j < 8; ++j)
            ah[rt][j].u = ahi4[((size_t)(rt0 + rt) * 8 + j) * 64 + lane];

    float m1[16], m2[16];
    unsigned int ii[16];
#pragma unroll
    for (int s = 0; s < 16; ++s) { m1[s] = FINF; m2[s] = FINF; ii[s] = 0; }

    int cbase = stripe * 1024;

    auto stage = [&](int ch, int buf) {
        const u32x4* g = bstr + (size_t)(stripe * 64 + ch * 2) * 512 + tid;
        u32x4* d = &lds[buf][0];
#pragma unroll
        for (int it = 0; it < 4; ++it) {
            __builtin_amdgcn_global_load_lds((const gu32*)(g + it * 256),
                                             (lu32*)(d + it * 256 + tid), 16, 0, 0);
        }
    };

    stage(0, 0);
    __syncthreads();

    for (int ch = 0; ch < 32; ++ch) {
        int cur = ch & 1;
        if (ch + 1 < 32) stage(ch + 1, cur ^ 1);

        float c2v[2]; int codeA[2]; unsigned int code16[2];
#pragma unroll
        for (int t = 0; t < 2; ++t) {
            int c = cbase + (ch * 2 + t) * 16 + colc;
            codeA[t] = c; code16[t] = ((unsigned int)c) << 16;
            c2v[t] = c2[c];
        }
        f32x4 acc[4][2];
#pragma unroll
        for (int rt = 0; rt < 4; ++rt)
#pragma unroll
            for (int t = 0; t < 2; ++t)
                acc[rt][t] = (f32x4){c2v[t], c2v[t], c2v[t], c2v[t]};

#pragma unroll
        for (int j = 0; j < 8; ++j) {
            V16 b0, b1;
            b0.u = lds[cur][(0 * 8 + j) * 64 + lane];
            b1.u = lds[cur][(1 * 8 + j) * 64 + lane];
#pragma unroll
            for (int rt = 0; rt < 4; ++rt) {      // 8 independent acc chains
                acc[rt][0] = __builtin_amdgcn_mfma_f32_16x16x32_bf16(ah[rt][j].s, b0.s, acc[rt][0], 0, 0, 0);
                acc[rt][1] = __builtin_amdgcn_mfma_f32_16x16x32_bf16(ah[rt][j].s, b1.s, acc[rt][1], 0, 0, 0);
            }
        }

#pragma unroll
        for (int t = 0; t < 2; ++t)
#pragma unroll
            for (int rt = 0; rt < 4; ++rt)
#pragma unroll
                for (int r = 0; r < 4; ++r) {
                    float d = acc[rt][t][r];
                    int s = rt * 4 + r;
                    bool lt1 = d < m1[s];
                    bool lt2 = d < m2[s];
                    unsigned int t1 = (ii[s] << 16) | (unsigned int)codeA[t];
                    unsigned int t2 = (ii[s] & 0xFFFFu) | code16[t];
                    m2[s] = lt1 ? m1[s] : (lt2 ? d : m2[s]);
                    ii[s] = lt1 ? t1 : (lt2 ? t2 : ii[s]);
                    m1[s] = lt1 ? d : m1[s];
                }
        __syncthreads();                          // joins waves + drains lds loads
    }

    // tail: per row-slot, extract top-4 of the 32 (m1,m2) across the 16 lanes
    // sharing the row (lanes with equal lane>>4; shfl_xor masks 1,2,4,8 stay
    // inside the group). Codes are distinct -> removal by idx is exact.
#pragma unroll
    for (int s = 0; s < 16; ++s) {
        int rt = s >> 2, r = s & 3;
        int row = (rt0 + rt) * 16 + (lane >> 4) * 4 + r;
        float v0 = m1[s], v1 = m2[s];
        int j0 = (int)(ii[s] & 0xFFFFu), j1 = (int)(ii[s] >> 16);
        int obase = (row * 8 + stripe) * 4;
#pragma unroll
        for (int k = 0; k < 4; ++k) {
            float bv; int bi;
            if (v1 < v0) { bv = v1; bi = j1; } else { bv = v0; bi = j0; }
#pragma unroll
            for (int mm = 1; mm < 16; mm <<= 1) {
                float ov = __shfl_xor(bv, mm, 64);
                int   oi = __shfl_xor(bi, mm, 64);
                if (ov < bv || (ov == bv && oi < bi)) { bv = ov; bi = oi; }
            }
            if ((lane & 15) == k) { cd[obase + k] = bv; ci[obase + k] = bi; }
            if (j0 == bi) v0 = FINF;
            if (j1 == bi) v1 = FINF;
        }
    }
}

// ---------------------------------------------------------------------------
// refine (stage 2): one wave per row, 32 candidates/row. Exact np f32
// semantics: z2 via f64 reduce, dot in f64 rounded once, then
// d1 = fl32(z2 - 2*Mf); d2 = fl32(d1 + c2); argmin, first-index ties.
// (Identical numerics to the R2 kernel that passed.)
// ---------------------------------------------------------------------------
__global__ __launch_bounds__(256)
void refine(const float* __restrict__ z, const float* __restrict__ cb,
            const float* __restrict__ c2,
            const float* __restrict__ cd, const int* __restrict__ ci,
            float* __restrict__ out, int* __restrict__ idxi) {
    int wid = threadIdx.x >> 6, lane = threadIdx.x & 63;
    int n = blockIdx.x * 4 + wid;
    int b = n >> 10, hw = n & 1023;
    float zq[4];
#pragma unroll
    for (int q = 0; q < 4; ++q)
        zq[q] = z[(size_t)(b * 256 + q * 64 + lane) * 1024 + hw];
    double zs = 0.0;
#pragma unroll
    for (int q = 0; q < 4; ++q) zs += (double)zq[q] * (double)zq[q];
#pragma unroll
    for (int m = 32; m >= 1; m >>= 1) zs += __shfl_xor(zs, m, 64);
    float z2v = (float)zs;

    float cdv = FINF; int civ = 0;
    if (lane < 32) { cdv = cd[n * 32 + lane]; civ = ci[n * 32 + lane]; }
    float rowmin = cdv;
#pragma unroll
    for (int m = 32; m >= 1; m >>= 1) rowmin = fminf(rowmin, __shfl_xor(rowmin, m, 64));
    bool active = (lane < 32) && (cdv <= rowmin + CAND_W);
    unsigned long long mask = __ballot(active);
    float bestd = FINF; int besti = 0x7fffffff;
    while (mask) {
        int k = __ffsll(mask) - 1;
        mask &= mask - 1;
        int cidx = __shfl(civ, k, 64);
        const float* crow = cb + (size_t)cidx * 256;
        double dot = 0.0;
#pragma unroll
        for (int q = 0; q < 4; ++q)
            dot += (double)zq[q] * (double)crow[q * 64 + lane];
#pragma unroll
        for (int m = 32; m >= 1; m >>= 1) dot += __shfl_xor(dot, m, 64);
        float Mf = (float)dot;
        float d1 = z2v - 2.0f * Mf;
        float d2 = d1 + c2[cidx];
        if (d2 < bestd || (d2 == bestd && cidx < besti)) { bestd = d2; besti = cidx; }
    }
    if (lane == 0) {
        idxi[n] = besti;
        out[4194304 + n] = (float)besti;
    }
}

// ---------------------------------------------------------------------------
// gather: z_q[b,d,h,w] = codebook[idx[b,h,w]][d], LDS transpose per (b,h)
// ---------------------------------------------------------------------------
__global__ void gather_out(const float* __restrict__ cb,
                           const int* __restrict__ idxi,
                           float* __restrict__ out) {
    __shared__ float tile[32][257];
    __shared__ int sidx[32];
    int b = blockIdx.x >> 5, h = blockIdx.x & 31;
    int tid = threadIdx.x;
    if (tid < 32) sidx[tid] = idxi[(b * 32 + h) * 32 + tid];
    __syncthreads();
    for (int e = tid; e < 8192; e += 256) {
        int w = e >> 8, d = e & 255;
        tile[w][d] = cb[(size_t)sidx[w] * 256 + d];
    }
    __syncthreads();
    for (int e = tid; e < 8192; e += 256) {
        int d = e >> 5, w = e & 31;
        out[(((size_t)b * 256 + d) * 32 + h) * 32 + w] = tile[w][d];
    }
}

// ---------------------------------------------------------------------------
extern "C" void kernel_launch(void* const* d_in, const int* in_sizes, int n_in,
                              void* d_out, int out_size, void* d_ws, size_t ws_size,
                              hipStream_t stream) {
    const float* z  = (const float*)d_in[0];      // [16,256,32,32]
    const float* cb = (const float*)d_in[1];      // [8192,256]
    float* out = (float*)d_out;                   // z_q (4194304) + idx (16384)
    char* w = (char*)d_ws;
    // ws layout: ahi 8M | bstr 4M | c2 32K | cd 2M | ci 2M | idxi 64K  (~16.1 MB)
    u32x4* ahi  = (u32x4*)(w);
    u32x4* bstr = (u32x4*)(w + 8388608);
    float* c2   = (float*)(w + 12582912);
    float* cd   = (float*)(w + 12615680);
    int*   ci   = (int*)  (w + 14712832);
    int*   idxi = (int*)  (w + 16809984);

    prep_a<<<2048, 256, 0, stream>>>(z, ahi);
    prep_b<<<1024, 256, 0, stream>>>(cb, bstr);
    calc_c2<<<2048, 256, 0, stream>>>(cb, c2);
    vq_main<<<512, 256, 0, stream>>>(ahi, bstr, c2, cd, ci);
    refine<<<4096, 256, 0, stream>>>(z, cb, c2, cd, ci, out, idxi);
    gather_out<<<512, 256, 0, stream>>>(cb, idxi, out);
}

// Round 4
// 188.304 us; speedup vs baseline: 2.2704x; 1.2248x over previous
//
#include <hip/hip_runtime.h>

typedef __attribute__((ext_vector_type(4))) unsigned int u32x4;
typedef __attribute__((ext_vector_type(4))) int i32x4;

union I16 { u32x4 u; i32x4 i; };

#define SA_INV   (127.0f / 12.0f)           // a = -2z, |a| <= 12 assumed (z tail 5.2)
#define SB_INV   (127.0f * 8192.0f)         // b in [-1/8192, 1/8192]
#define INV_SASB ((127.0 * 127.0 * 8192.0) / 12.0)   // 1/(sa*sb) ~ 1.101e7
#define WI       4500                        // refine window in int-dist units (~4e-4)
#define FINF     3.4e38f

__device__ __forceinline__ int q8(float x, float s) {
    int q = (int)__builtin_rintf(x * s);
    return q < -127 ? -127 : (q > 127 ? 127 : q);
}

// ---------------------------------------------------------------------------
// prep_a: z_e [16,256,32,32] fp32 NCHW -> i8 A fragments (a = -2z quantized).
// 16x16x64 i8 A-layout (bf16-pattern generalized): lane l of row-tile rt,
// k-step j holds A[rt*16+(l&15)][k = j*64 + (l>>4)*16 .. +16] as 4 dwords,
// bytes little-endian = increasing k.
// ---------------------------------------------------------------------------
__global__ void prep_a(const float* __restrict__ z, u32x4* __restrict__ ahi) {
    int o = blockIdx.x * 256 + threadIdx.x;       // 262144 total
    int l = o & 63, j = (o >> 6) & 3, rtg = o >> 8;
    int n = rtg * 16 + (l & 15);                  // row = b*1024 + h*32 + w
    int k0 = j * 64 + ((l >> 4) << 4);
    const float* src = z + ((size_t)(n >> 10) * 256 + k0) * 1024 + (n & 1023);
    u32x4 v;
#pragma unroll
    for (int d = 0; d < 4; ++d) {
        unsigned int w = 0;
#pragma unroll
        for (int b = 0; b < 4; ++b) {
            int q = q8(-2.0f * src[(size_t)(d * 4 + b) * 1024], SA_INV);
            w |= ((unsigned int)(q & 255)) << (8 * b);
        }
        v[d] = w;
    }
    ahi[o] = v;
}

// ---------------------------------------------------------------------------
// prep_b: codebook [8192,256] fp32 -> i8 B fragments in streaming order:
// stream u32x4 index (stripe*8 + ch)*1024 + (t*4 + j)*64 + l, where
// code = ((stripe*8+ch)*4 + t)*16 + (l&15), k = j*64 + (l>>4)*16 .. +16.
// ---------------------------------------------------------------------------
__global__ void prep_b(const float* __restrict__ cb, u32x4* __restrict__ bstr) {
    int o = blockIdx.x * 256 + threadIdx.x;       // 131072 total
    int l = o & 63, j = (o >> 6) & 3, ct = o >> 8;    // ct in [0,512)
    int code = ct * 16 + (l & 15);
    int k0 = j * 64 + ((l >> 4) << 4);
    const float* src = cb + (size_t)code * 256 + k0;
    u32x4 v;
#pragma unroll
    for (int d = 0; d < 4; ++d) {
        unsigned int w = 0;
#pragma unroll
        for (int b = 0; b < 4; ++b) {
            int q = q8(src[d * 4 + b], SB_INV);
            w |= ((unsigned int)(q & 255)) << (8 * b);
        }
        v[d] = w;
    }
    int stripe = ct >> 5, rr = ct & 31, ch = rr >> 2, t = rr & 3;
    bstr[(size_t)((stripe * 8 + ch) * 1024) + (t * 4 + j) * 64 + l] = v;
}

// ---------------------------------------------------------------------------
// calc_c2: c2[k] (f32, for refine) and ibt[k] = ((round(c2/(sa*sb)) + 2^18)
// << 6) | tcode  where tcode = (k>>4)&31 — the key-bias table for vq_main.
// ---------------------------------------------------------------------------
__global__ void calc_c2(const float* __restrict__ cb, float* __restrict__ c2,
                        unsigned int* __restrict__ ibt) {
    int wid = threadIdx.x >> 6, lane = threadIdx.x & 63;
    int code = blockIdx.x * 4 + wid;
    const float* row = cb + (size_t)code * 256;
    float s = 0.f;
#pragma unroll
    for (int q = 0; q < 4; ++q) { float v = row[q * 64 + lane]; s += v * v; }
#pragma unroll
    for (int m = 32; m >= 1; m >>= 1) s += __shfl_xor(s, m, 64);
    if (lane == 0) {
        c2[code] = s;
        int ib = (int)__builtin_rintf(s * (float)INV_SASB);
        ibt[code] = (((unsigned int)(ib + 262144)) << 6) | (unsigned int)((code >> 4) & 31);
    }
}

// ---------------------------------------------------------------------------
// prep_zt: z transposed to row-major [16384][256] + z2f (f64-accum sum z^2).
// (R2-verified.)
// ---------------------------------------------------------------------------
__global__ void prep_zt(const float* __restrict__ z, float* __restrict__ zt,
                        float* __restrict__ z2f) {
    __shared__ float tile[32][257];
    int b = blockIdx.x >> 5, h = blockIdx.x & 31;
    int tid = threadIdx.x;
    for (int e = tid; e < 8192; e += 256) {
        int d = e >> 5, w = e & 31;
        tile[w][d] = z[((size_t)(b * 256 + d) * 32 + h) * 32 + w];
    }
    __syncthreads();
    for (int e = tid; e < 8192; e += 256) {
        int w = e >> 8, d = e & 255;
        zt[((size_t)(b * 1024 + h * 32 + w)) * 256 + d] = tile[w][d];
    }
    if (tid < 32) {
        double s = 0.0;
        for (int d = 0; d < 256; ++d) { double v = (double)tile[tid][d]; s += v * v; }
        z2f[b * 1024 + h * 32 + tid] = (float)s;
    }
}

// ---------------------------------------------------------------------------
// vq_main: 1024 blocks = 64 rowgroups x 16 stripes. Wave holds 64 rows of i8
// A in 64 VGPRs; stripe = 512 codes scanned in 8 chunks of 64 codes
// (4 code-tiles processed t-sequentially), double-buffered 2x16KB LDS.
// Distances stay in int domain; key = ((acc+ibias+2^18)<<6)|tcode via one
// lshl_add with prefetched ibt. Branchless top-2 per (lane,slot):
// disp=max(m1,key); m1=min(m1,key); m2=min(m2,disp). Tail extracts top-3
// per (row,stripe) -> 48 candidates/row.
// ---------------------------------------------------------------------------
typedef __attribute__((address_space(1))) unsigned int gu32;
typedef __attribute__((address_space(3))) unsigned int lu32;

__global__ __launch_bounds__(256)
void vq_main(const u32x4* __restrict__ ahi4, const u32x4* __restrict__ bstr,
             const unsigned int* __restrict__ ibt,
             unsigned int* __restrict__ cd, int* __restrict__ ci) {
    __shared__ u32x4 lds[2][1024];                // 2 x 16 KB
    int tid = threadIdx.x;
    int wid = tid >> 6, lane = tid & 63;
    int stripe = blockIdx.x & 15;
    int rg = blockIdx.x >> 4;                     // 0..63
    int colc = lane & 15;
    int rt0 = rg * 16 + wid * 4;                  // wave's 4 row-tiles (64 rows)

    I16 ah[4][4];
#pragma unroll
    for (int rt = 0; rt < 4; ++rt)
#pragma unroll
        for (int j = 0; j < 4; ++j)
            ah[rt][j].u = ahi4[((size_t)(rt0 + rt) * 4 + j) * 64 + lane];

    unsigned int m1[16], m2[16];
#pragma unroll
    for (int s = 0; s < 16; ++s) { m1[s] = 0xFFFFFFFFu; m2[s] = 0xFFFFFFFFu; }

    i32x4 zc = (i32x4){0, 0, 0, 0};

    auto stage = [&](int ch, int buf) {
        const u32x4* g = bstr + (size_t)(stripe * 8 + ch) * 1024 + tid;
        u32x4* d = &lds[buf][0];
#pragma unroll
        for (int it = 0; it < 4; ++it) {
            __builtin_amdgcn_global_load_lds((const gu32*)(g + it * 256),
                                             (lu32*)(d + it * 256 + tid), 16, 0, 0);
        }
    };

    stage(0, 0);
    __syncthreads();

    for (int ch = 0; ch < 8; ++ch) {
        int cur = ch & 1;
        if (ch + 1 < 8) stage(ch + 1, cur ^ 1);

        unsigned int ibtv[4];
#pragma unroll
        for (int t = 0; t < 4; ++t)
            ibtv[t] = ibt[stripe * 512 + ch * 64 + t * 16 + colc];

#pragma unroll
        for (int t = 0; t < 4; ++t) {
            i32x4 acc[4];
            {
                I16 bf; bf.u = lds[cur][(t * 4 + 0) * 64 + lane];
#pragma unroll
                for (int rt = 0; rt < 4; ++rt)
                    acc[rt] = __builtin_amdgcn_mfma_i32_16x16x64_i8(ah[rt][0].i, bf.i, zc, 0, 0, 0);
            }
#pragma unroll
            for (int j = 1; j < 4; ++j) {
                I16 bf; bf.u = lds[cur][(t * 4 + j) * 64 + lane];
#pragma unroll
                for (int rt = 0; rt < 4; ++rt)
                    acc[rt] = __builtin_amdgcn_mfma_i32_16x16x64_i8(ah[rt][j].i, bf.i, acc[rt], 0, 0, 0);
            }
#pragma unroll
            for (int rt = 0; rt < 4; ++rt)
#pragma unroll
                for (int r = 0; r < 4; ++r) {
                    unsigned int key = (((unsigned int)acc[rt][r]) << 6) + ibtv[t];
                    int s = rt * 4 + r;
                    unsigned int disp = m1[s] > key ? m1[s] : key;   // v_max_u32
                    m1[s] = m1[s] < key ? m1[s] : key;               // v_min_u32
                    m2[s] = m2[s] < disp ? m2[s] : disp;             // v_min_u32
                }
        }
        __syncthreads();                          // joins waves + drains lds DMA
    }

    // tail: per row-slot, top-3 of the 32 (m1,m2) across the 16 lanes sharing
    // the row (equal lane>>4; xor masks 1,2,4,8 stay in-group). Key embeds
    // tcode; full code = stripe*512 + (key&63)*16 + colc.
#pragma unroll
    for (int s = 0; s < 16; ++s) {
        int rt = s >> 2, r = s & 3;
        int row = (rt0 + rt) * 16 + (lane >> 4) * 4 + r;
        unsigned int v0 = m1[s], v1 = m2[s];
        int c0 = stripe * 512 + (int)(v0 & 63) * 16 + colc;
        int c1 = stripe * 512 + (int)(v1 & 63) * 16 + colc;
        int obase = (row * 16 + stripe) * 3;
#pragma unroll
        for (int k = 0; k < 3; ++k) {
            unsigned int bv; int bi;
            if (v1 < v0) { bv = v1; bi = c1; } else { bv = v0; bi = c0; }
#pragma unroll
            for (int mm = 1; mm < 16; mm <<= 1) {
                unsigned int ov = __shfl_xor(bv, mm, 64);
                int oi = __shfl_xor(bi, mm, 64);
                if (ov < bv || (ov == bv && oi < bi)) { bv = ov; bi = oi; }
            }
            if (colc == k) { cd[obase + k] = bv; ci[obase + k] = bi; }
            if (bi == c0) v0 = 0xFFFFFFFFu;
            if (bi == c1) v1 = 0xFFFFFFFFu;
        }
    }
}

// ---------------------------------------------------------------------------
// refine: one wave per row, 48 candidates. Exact np f32 semantics (verified
// in R2/R3): f64 dot rounded once, d1 = fl32(z2 - 2*Mf), d2 = fl32(d1 + c2),
// argmin with first-index ties. Window filter on int keys.
// ---------------------------------------------------------------------------
__global__ __launch_bounds__(256)
void refine(const float* __restrict__ zt, const float* __restrict__ z2f,
            const float* __restrict__ cb, const float* __restrict__ c2,
            const unsigned int* __restrict__ cd, const int* __restrict__ ci,
            float* __restrict__ out, int* __restrict__ idxi) {
    int wid = threadIdx.x >> 6, lane = threadIdx.x & 63;
    int n = blockIdx.x * 4 + wid;
    float zq[4];
#pragma unroll
    for (int q = 0; q < 4; ++q) zq[q] = zt[(size_t)n * 256 + q * 64 + lane];
    float z2v = z2f[n];

    unsigned int kd = 0xFFFFFFFFu; int civ = 0;
    if (lane < 48) { kd = cd[n * 48 + lane]; civ = ci[n * 48 + lane]; }
    unsigned int rm = kd;
#pragma unroll
    for (int m = 32; m >= 1; m >>= 1) {
        unsigned int o = __shfl_xor(rm, m, 64);
        rm = o < rm ? o : rm;
    }
    bool active = (lane < 48) && ((kd >> 6) <= (rm >> 6) + WI);
    unsigned long long mask = __ballot(active);
    float bestd = FINF; int besti = 0x7fffffff;
    while (mask) {
        int k = __ffsll(mask) - 1;
        mask &= mask - 1;
        int cidx = __shfl(civ, k, 64);
        const float* crow = cb + (size_t)cidx * 256;
        double dot = 0.0;
#pragma unroll
        for (int q = 0; q < 4; ++q)
            dot += (double)zq[q] * (double)crow[q * 64 + lane];
#pragma unroll
        for (int m = 32; m >= 1; m >>= 1) dot += __shfl_xor(dot, m, 64);
        float Mf = (float)dot;
        float d1 = z2v - 2.0f * Mf;
        float d2 = d1 + c2[cidx];
        if (d2 < bestd || (d2 == bestd && cidx < besti)) { bestd = d2; besti = cidx; }
    }
    if (lane == 0) {
        idxi[n] = besti;
        out[4194304 + n] = (float)besti;
    }
}

// ---------------------------------------------------------------------------
// gather: z_q[b,d,h,w] = codebook[idx[b,h,w]][d], LDS transpose per (b,h)
// ---------------------------------------------------------------------------
__global__ void gather_out(const float* __restrict__ cb,
                           const int* __restrict__ idxi,
                           float* __restrict__ out) {
    __shared__ float tile[32][257];
    __shared__ int sidx[32];
    int b = blockIdx.x >> 5, h = blockIdx.x & 31;
    int tid = threadIdx.x;
    if (tid < 32) sidx[tid] = idxi[(b * 32 + h) * 32 + tid];
    __syncthreads();
    for (int e = tid; e < 8192; e += 256) {
        int w = e >> 8, d = e & 255;
        tile[w][d] = cb[(size_t)sidx[w] * 256 + d];
    }
    __syncthreads();
    for (int e = tid; e < 8192; e += 256) {
        int d = e >> 5, w = e & 31;
        out[(((size_t)b * 256 + d) * 32 + h) * 32 + w] = tile[w][d];
    }
}

// ---------------------------------------------------------------------------
extern "C" void kernel_launch(void* const* d_in, const int* in_sizes, int n_in,
                              void* d_out, int out_size, void* d_ws, size_t ws_size,
                              hipStream_t stream) {
    const float* z  = (const float*)d_in[0];      // [16,256,32,32]
    const float* cb = (const float*)d_in[1];      // [8192,256]
    float* out = (float*)d_out;                   // z_q (4194304) + idx (16384)
    char* w = (char*)d_ws;
    // ws layout (bytes):
    //   ahi   0        .. 4,194,304   (4MB)   [idxi overlaid after vq_main]
    //   bstr  4,194,304 .. 6,291,456  (2MB)
    //   zt    6,291,456 .. 23,068,672 (16MB)
    //   c2    23,068,672 (+32KB) | ibt 23,101,440 (+32KB) | z2f 23,134,208 (+64KB)
    //   cd    23,199,744 (+3MB) | ci 26,345,472 (+3MB)  -> end 29,491,200
    u32x4* ahi  = (u32x4*)(w);
    u32x4* bstr = (u32x4*)(w + 4194304);
    float* zt   = (float*)(w + 6291456);
    float* c2   = (float*)(w + 23068672);
    unsigned int* ibt = (unsigned int*)(w + 23101440);
    float* z2f  = (float*)(w + 23134208);
    unsigned int* cd = (unsigned int*)(w + 23199744);
    int*   ci   = (int*)(w + 26345472);
    int*   idxi = (int*)(w);                      // overlays dead ahi region

    prep_a<<<1024, 256, 0, stream>>>(z, ahi);
    prep_b<<<512, 256, 0, stream>>>(cb, bstr);
    calc_c2<<<2048, 256, 0, stream>>>(cb, c2, ibt);
    prep_zt<<<512, 256, 0, stream>>>(z, zt, z2f);
    vq_main<<<1024, 256, 0, stream>>>(ahi, bstr, ibt, cd, ci);
    refine<<<4096, 256, 0, stream>>>(zt, z2f, cb, c2, cd, ci, out, idxi);
    gather_out<<<512, 256, 0, stream>>>(cb, idxi, out);
}